// Round 16
// baseline (106.910 us; speedup 1.0000x reference)
//
#include <hip/hip_runtime.h>
#include <hip/hip_bf16.h>
#include <stdint.h>

typedef __bf16 bf16;
typedef __bf16 bf16x2 __attribute__((ext_vector_type(2)));
typedef __bf16 bf16x4 __attribute__((ext_vector_type(4)));
typedef __bf16 bf16x8 __attribute__((ext_vector_type(8)));
typedef float f32x4 __attribute__((ext_vector_type(4)));
typedef float f32x16 __attribute__((ext_vector_type(16)));
typedef unsigned int u32x4 __attribute__((ext_vector_type(4)));
typedef int i32x2 __attribute__((ext_vector_type(2)));

#define AS1 __attribute__((address_space(1)))
#define AS3 __attribute__((address_space(3)))

// B=4 S=2048 E=512 H=8 D=64; tokens M = 8192.

// ---------------- prep (fused): z<4 -> W[z] transpose-cast; z>=4 -> x cast ----------------
__global__ void prep_kernel(const float* __restrict__ x,
                            const float* __restrict__ W0, const float* __restrict__ W1,
                            const float* __restrict__ W2, const float* __restrict__ W3,
                            bf16* __restrict__ xb, bf16* __restrict__ Wt) {
  __shared__ bf16 t[64][65];
  const int z = blockIdx.z;
  if (z < 4) {
    const float* W = z == 0 ? W0 : z == 1 ? W1 : z == 2 ? W2 : W3;
    bf16* dst = Wt + (size_t)z * 262144;
    const int c = threadIdx.x & 63, r0 = threadIdx.x >> 6;
    const int bn = blockIdx.x * 64, bk = blockIdx.y * 64;
#pragma unroll
    for (int i = 0; i < 16; ++i) {
      int r = r0 * 16 + i;
      t[c][r] = (bf16)W[(size_t)(bk + r) * 512 + bn + c];
    }
    __syncthreads();
#pragma unroll
    for (int i = 0; i < 16; ++i) {
      int n = r0 * 16 + i;
      dst[(size_t)(bn + n) * 512 + bk + c] = t[n][c];
    }
  } else {
    // cast slice: 64 z-slices x 64 blocks x 256 threads x 1 float4 = 1,048,576 float4
    int bi = (z - 4) * 64 + blockIdx.y * 8 + blockIdx.x;
    int i = bi * 256 + threadIdx.x;
    float4 v = reinterpret_cast<const float4*>(x)[i];
    bf16x4 o = { (bf16)v.x, (bf16)v.y, (bf16)v.z, (bf16)v.w };
    *reinterpret_cast<bf16x4*>(xb + (size_t)i * 4) = o;
  }
}

// ---------------- GEMM (TN), BM=64 x BN tiles (R14 proven) ----------------
// MODE 0: bf16 scatter to [B,H,S,D] (q|k|v, bias+scale); MODE 1: f32 [M][512].
template<int BN, int MODE>
__global__ __launch_bounds__(256, 4) void gemm64_kernel(
    const bf16* __restrict__ A, const bf16* __restrict__ Bt,
    const float* __restrict__ bq, const float* __restrict__ bk,
    const float* __restrict__ bv, bf16* __restrict__ out_bf,
    float* __restrict__ out_f, float qscale)
{
  constexpr int NT = BN / 32;               // per-wave n-frags (wave = 32 x BN/2)
  __shared__ bf16 As[64 * 64];
  __shared__ bf16 Bs[BN * 64];
  const int tid = threadIdx.x, lane = tid & 63, w = tid >> 6;
  const int wm = w >> 1, wn = w & 1;        // 2x2 wave grid
  const int m0 = blockIdx.x * 64, n0g = blockIdx.y * BN;
  const int cl = lane & 15, hi = lane >> 4;
  const int lr = lane >> 3;
  const int cofs = ((lane & 7) << 4) ^ (lr << 4);   // pre-swizzled source byte col

  f32x4 acc[2][NT] = {};

  for (int kt = 0; kt < 512; kt += 64) {
    __syncthreads();
#pragma unroll
    for (int c = 0; c < 2; ++c) {           // A: 64 rows, 2 instr/wave
      int rA = m0 + w * 16 + c * 8 + lr;
      const void* srcA = (const char*)A + ((size_t)rA * 512 + kt) * 2 + cofs;
      void* dstA = (char*)As + w * 2048 + c * 1024;
      __builtin_amdgcn_global_load_lds((const AS1 void*)srcA, (AS3 void*)dstA, 16, 0, 0);
    }
#pragma unroll
    for (int c = 0; c < NT; ++c) {          // B: BN rows, NT instr/wave
      int rB = n0g + w * (BN / 4) + c * 8 + lr;
      const void* srcB = (const char*)Bt + ((size_t)rB * 512 + kt) * 2 + cofs;
      void* dstB = (char*)Bs + w * (BN / 4) * 128 + c * 1024;
      __builtin_amdgcn_global_load_lds((const AS1 void*)srcB, (AS3 void*)dstB, 16, 0, 0);
    }
    __syncthreads();
#pragma unroll
    for (int ks = 0; ks < 2; ++ks) {
      bf16x8 af[2], bfv[NT];
#pragma unroll
      for (int mt = 0; mt < 2; ++mt) {
        int r = wm * 32 + mt * 16 + cl;
        int cb = (ks * 64 + (hi << 4)) ^ ((r & 7) << 4);
        af[mt] = *(const bf16x8*)((const char*)As + r * 128 + cb);
      }
#pragma unroll
      for (int nt = 0; nt < NT; ++nt) {
        int r = wn * (BN / 2) + nt * 16 + cl;
        int cb = (ks * 64 + (hi << 4)) ^ ((r & 7) << 4);
        bfv[nt] = *(const bf16x8*)((const char*)Bs + r * 128 + cb);
      }
#pragma unroll
      for (int mt = 0; mt < 2; ++mt)
#pragma unroll
        for (int nt = 0; nt < NT; ++nt)
          acc[mt][nt] = __builtin_amdgcn_mfma_f32_16x16x32_bf16(af[mt], bfv[nt], acc[mt][nt], 0, 0, 0);
    }
  }

  if (MODE == 0) {
    const int which = n0g >> 9;             // 0=q 1=k 2=v (BN=128 tile never straddles)
    const float* bias = which == 0 ? bq : (which == 1 ? bk : bv);
    const float scale = which == 0 ? qscale : 1.0f;
    bf16* outb = out_bf + (size_t)which * 4194304;
    const int ncol0 = n0g & 511;
#pragma unroll
    for (int mt = 0; mt < 2; ++mt) {
#pragma unroll
      for (int nt = 0; nt < NT; ++nt) {
        int row0 = m0 + wm * 32 + mt * 16 + hi * 4;
        int col = ncol0 + wn * (BN / 2) + nt * 16 + cl;
        float bvl = bias[col];
        int h = col >> 6, d = col & 63;
#pragma unroll
        for (int i = 0; i < 4; ++i) {
          float vv = (acc[mt][nt][i] + bvl) * scale;
          int row = row0 + i;
          int b = row >> 11, s = row & 2047;
          outb[(((size_t)(b * 8 + h)) * 2048 + s) * 64 + d] = (bf16)vv;
        }
      }
    }
  } else {
#pragma unroll
    for (int mt = 0; mt < 2; ++mt) {
#pragma unroll
      for (int nt = 0; nt < NT; ++nt) {
        int row0 = m0 + wm * 32 + mt * 16 + hi * 4;
        int col = n0g + wn * (BN / 2) + nt * 16 + cl;
        float bvl = bq[col];
#pragma unroll
        for (int i = 0; i < 4; ++i)
          out_f[(size_t)(row0 + i) * 512 + col] = acc[mt][nt][i] + bvl;
      }
    }
  }
}

// cross-half (lane ^ 32) read via v_permlane32_swap_b32 (VALU pipe; m255: 1.20x
// vs the ds_bpermute that __shfl_xor(.,32) lowers to). Returns partner's value.
__device__ __forceinline__ float xhalf_get(float x, int H) {
#if __has_builtin(__builtin_amdgcn_permlane32_swap)
  int xi = __builtin_bit_cast(int, x);
  i32x2 r = __builtin_amdgcn_permlane32_swap(xi, xi, false, false);
  // new_vdst lanes>=32 hold src lanes 0-31 (= partner for H=1);
  // new_vsrc lanes<32 hold dst lanes 32-63 (= partner for H=0).
  return __builtin_bit_cast(float, H ? r[0] : r[1]);
#else
  (void)H;
  return __shfl_xor(x, 32);
#endif
}

// ---------------- flash attention, swapped-QK^T 32x32, IN-BLOCK split-KV ----------------
// grid (32 bh, 16 qb) x 512 threads (8 waves); waves 0-3 keys [0,1024), 4-7 [1024,2048).
// R16 changes (softmax cross-lane ops off the LDS pipe / off the critical path):
//  (1) pmax cross-half sync via permlane32_swap (VALU) instead of shfl/ds_bpermute
//      — this exchange sits on the QK^T -> exp critical path.
//  (2) l cross-half sum DEFERRED to epilogue (linear in P; m already synced per
//      tile) — removes 1 exchange per ct (32 total), adds 1 at the end.
//  (3) max tree as fmax triples -> clang fuses v_max3_f32 (T17).
// NOTE: per-half m is provably invalid (PV's B-frag mixes both halves' P in one
// MFMA chain), so the per-tile m sync must stay.
__global__ __launch_bounds__(512, 4) void attn_kernel(
    const bf16* __restrict__ q, const bf16* __restrict__ k,
    const bf16* __restrict__ v, bf16* __restrict__ merged)
{
  __shared__ union SU {
    struct { bf16 K[2][2][4096]; bf16 V[2][2][4096]; } s;  // [half][buf][row*64] : 64 KB
    struct {
      float EPf[4][64][33];                                 // fp32 merge buffer (33 KB)
      float Msh[8][32];
      float Lsh[8][32];
      bf16  EP[4][2304];                                    // per-qwave [q][72] transpose
    } e;
  } u;
  __shared__ bf16 VT[2][4096];      // per-half [d][key], byte-col XOR-swizzled

  const int tid = threadIdx.x, lane = tid & 63, w = tid >> 6;
  const int wl = w & 3, half = w >> 2;
  const int ht = tid & 255;         // thread id within half
  const int l31 = lane & 31, H = lane >> 5;
  const int bh = blockIdx.x, qb = blockIdx.y;
  const int b = bh >> 3, h = bh & 7;
  const int kv0 = half << 10;       // 0 or 1024

  const bf16* Q  = q + (size_t)bh * 2048 * 64;
  const bf16* Kp = k + (size_t)bh * 2048 * 64;
  const bf16* Vp = v + (size_t)bh * 2048 * 64;

  const int q0 = qb * 128 + wl * 32;
  const int kp = ht & 31;           // key pair for VT staging (within half)
  const int dblk = (ht >> 5) * 8;   // 8 d-rows per thread group (within half)

  const int lr8 = lane >> 3;        // row within 8-row staging group
  const int lc = lane & 7;          // 16B chunk within 128B row

#define STAGE_KV(BUF, KEYBASE)                                                            \
  {                                                                                       \
    _Pragma("unroll")                                                                     \
    for (int i = 0; i < 2; ++i) {                                                         \
      int row = wl * 16 + i * 8 + lr8;                                                    \
      const void* sK = (const char*)Kp + ((size_t)((KEYBASE) + row)) * 128 + ((lc ^ lr8) << 4); \
      void* dK = (char*)u.s.K[half][BUF] + wl * 2048 + i * 1024;                          \
      __builtin_amdgcn_global_load_lds((const AS1 void*)sK, (AS3 void*)dK, 16, 0, 0);     \
      const void* sV = (const char*)Vp + ((size_t)((KEYBASE) + row)) * 128 + ((lc ^ ((row >> 1) & 7)) << 4); \
      void* dV = (char*)u.s.V[half][BUF] + wl * 2048 + i * 1024;                          \
      __builtin_amdgcn_global_load_lds((const AS1 void*)sV, (AS3 void*)dV, 16, 0, 0);     \
    }                                                                                     \
  }

  // Q as B-operand frags (one-time)
  bf16x8 qf[4];
#pragma unroll
  for (int s = 0; s < 4; ++s)
    qf[s] = *(const bf16x8*)(Q + (size_t)(q0 + l31) * 64 + s * 16 + H * 8);

  f32x16 oacc[2] = {};              // O^T[d][q]: d = dt*32 + (r&3)+8*(r>>2)+4*H
  float m_run = -1e30f, l_run = 0.f;   // l_run: OWN-half key sums only (summed at end)

  STAGE_KV(0, kv0);
  __syncthreads();                  // buf0 ready (implicit vmcnt(0) drain)

  int cur = 0;
  for (int kt0 = kv0; kt0 < kv0 + 1024; kt0 += 64) {
    // ---- build VT[half] for cur tile from V-lds (swizzled, ~2-way free) ----
    {
      const char* vb = (const char*)u.s.V[half][cur];
      const int vofs = (((ht >> 5) ^ (kp & 7)) << 4);
      bf16x8 vs0 = *(const bf16x8*)(vb + (2 * kp) * 128 + vofs);
      bf16x8 vs1 = *(const bf16x8*)(vb + (2 * kp + 1) * 128 + vofs);
#pragma unroll
      for (int j = 0; j < 8; ++j) {
        int d = dblk + j;
        bf16x2 t = { vs0[j], vs1[j] };
        *(bf16x2*)((char*)&VT[half][0] + d * 128 + ((4 * kp) ^ ((d & 7) << 4))) = t;
      }
    }
    __syncthreads();                // barrier A: VT ready (no vmem outstanding)

    // issue next tile's K/V staging — drains at barrier B, covered by compute
    if (kt0 + 64 < kv0 + 1024) STAGE_KV(cur ^ 1, kt0 + 64);

    const char* kb = (const char*)u.s.K[half][cur];

    // ---- ct-sequential: QK^T chunk -> softmax chunk -> PV chunk (32 keys each) ----
#pragma unroll
    for (int ct = 0; ct < 2; ++ct) {
      f32x16 sc = {};
      {
        const int krow = ct * 32 + l31;
        bf16x8 kf[4];
#pragma unroll
        for (int s = 0; s < 4; ++s)
          kf[s] = *(const bf16x8*)(kb + krow * 128 + ((s * 32 + H * 16) ^ ((l31 & 7) << 4)));
#pragma unroll
        for (int s = 0; s < 4; ++s)
          sc = __builtin_amdgcn_mfma_f32_32x32x16_bf16(kf[s], qf[s], sc, 0, 0, 0);
      }

      // lane-local online softmax with defer-max (T13); max3-fused tree
      float mx[8];
#pragma unroll
      for (int r = 0; r < 8; ++r) mx[r] = fmaxf(sc[r], sc[r + 8]);
      float t0 = fmaxf(fmaxf(mx[0], mx[1]), mx[2]);   // v_max3
      float t1 = fmaxf(fmaxf(mx[3], mx[4]), mx[5]);   // v_max3
      float t2 = fmaxf(mx[6], mx[7]);
      float pmax = fmaxf(fmaxf(t0, t1), t2);          // v_max3
      pmax = fmaxf(pmax, xhalf_get(pmax, H));         // cross-half sync (VALU permlane)
      if (__any(pmax > m_run + 8.f)) {
        float mn = fmaxf(m_run, pmax);
        float alpha = exp2f(m_run - mn);
        m_run = mn;
        l_run *= alpha;
#pragma unroll
        for (int dt = 0; dt < 2; ++dt)
#pragma unroll
          for (int r = 0; r < 16; ++r) oacc[dt][r] *= alpha;
      }
#pragma unroll
      for (int r = 0; r < 16; ++r) sc[r] = exp2f(sc[r] - m_run);

      float sm[8];
#pragma unroll
      for (int r = 0; r < 8; ++r) sm[r] = sc[r] + sc[r + 8];
      l_run += ((sm[0] + sm[1]) + (sm[2] + sm[3])) + ((sm[4] + sm[5]) + (sm[6] + sm[7]));
      // NOTE: cross-half l sum deferred to epilogue (m is synced, l is linear)

      // in-register P -> bf16 B-frags (cross-half via permlane32_swap), then PV
#pragma unroll
      for (int hf = 0; hf < 2; ++hf) {
        const int ks = ct * 2 + hf;
        const int g0 = 8 * hf;
        bf16x2 pa0 = { (bf16)sc[g0 + 0], (bf16)sc[g0 + 1] };
        bf16x2 pa1 = { (bf16)sc[g0 + 2], (bf16)sc[g0 + 3] };
        bf16x2 pb0 = { (bf16)sc[g0 + 4], (bf16)sc[g0 + 5] };
        bf16x2 pb1 = { (bf16)sc[g0 + 6], (bf16)sc[g0 + 7] };
        unsigned a0 = __builtin_bit_cast(unsigned, pa0);
        unsigned a1 = __builtin_bit_cast(unsigned, pa1);
        unsigned b0 = __builtin_bit_cast(unsigned, pb0);
        unsigned b1 = __builtin_bit_cast(unsigned, pb1);
        u32x4 pw;
#if __has_builtin(__builtin_amdgcn_permlane32_swap)
        i32x2 r0 = __builtin_amdgcn_permlane32_swap((int)a0, (int)b0, false, false);
        i32x2 r1 = __builtin_amdgcn_permlane32_swap((int)a1, (int)b1, false, false);
        pw[0] = (unsigned)r0[0]; pw[1] = (unsigned)r1[0];
        pw[2] = (unsigned)r0[1]; pw[3] = (unsigned)r1[1];
#else
        unsigned oa0 = (unsigned)__shfl_xor((int)a0, 32);
        unsigned oa1 = (unsigned)__shfl_xor((int)a1, 32);
        unsigned ob0 = (unsigned)__shfl_xor((int)b0, 32);
        unsigned ob1 = (unsigned)__shfl_xor((int)b1, 32);
        pw[0] = H ? ob0 : a0; pw[1] = H ? ob1 : a1;
        pw[2] = H ? b0 : oa0; pw[3] = H ? b1 : oa1;
#endif
        bf16x8 pf = __builtin_bit_cast(bf16x8, pw);
#pragma unroll
        for (int dt = 0; dt < 2; ++dt) {
          int d = dt * 32 + l31;
          bf16x8 vf = *(const bf16x8*)((const char*)&VT[half][0] + d * 128 + ((ks * 32 + H * 16) ^ ((d & 7) << 4)));
          oacc[dt] = __builtin_amdgcn_mfma_f32_32x32x16_bf16(vf, pf, oacc[dt], 0, 0, 0);
        }
      }
    }

    __syncthreads();                // barrier B: prefetch landed; VT/K reads done
    cur ^= 1;
  }

  // ---- deferred cross-half l sum (m synced; both lanes of a pair share m_run) ----
  l_run += xhalf_get(l_run, H);

  // ---- in-block merge of the two key-halves (fp32 via LDS) ----
  if (H == 0) { u.e.Msh[w][l31] = m_run; u.e.Lsh[w][l31] = l_run; }
  __syncthreads();
  const int pw2 = w ^ 4;
  float m_o = u.e.Msh[pw2][l31], l_o = u.e.Lsh[pw2][l31];
  float Mt = fmaxf(m_run, m_o);
  float denom = exp2f(m_run - Mt) * l_run + exp2f(m_o - Mt) * l_o;
  float scale = exp2f(m_run - Mt) / denom;
  if (w < 4) {
    float* ep = &u.e.EPf[wl][lane][0];
#pragma unroll
    for (int dt = 0; dt < 2; ++dt)
#pragma unroll
      for (int r = 0; r < 16; ++r) ep[dt * 16 + r] = oacc[dt][r] * scale;
  }
  __syncthreads();
  if (w >= 4) {
    const float* ep = &u.e.EPf[wl][lane][0];
#pragma unroll
    for (int dt = 0; dt < 2; ++dt)
#pragma unroll
      for (int r = 0; r < 16; ++r) {
        float val = ep[dt * 16 + r] + oacc[dt][r] * scale;
        int d = dt * 32 + (r & 3) + 8 * (r >> 2) + 4 * H;
        u.e.EP[wl][l31 * 72 + d] = (bf16)val;
      }
    __builtin_amdgcn_s_waitcnt(0);  // per-wave LDS region, same-wave readback
#pragma unroll
    for (int g = 0; g < 4; ++g) {
      int qr = g * 8 + (lane >> 3);
      bf16x8 row = *(const bf16x8*)&u.e.EP[wl][qr * 72 + (lane & 7) * 8];
      *(bf16x8*)(merged + (size_t)(b * 2048 + q0 + qr) * 512 + h * 64 + (lane & 7) * 8) = row;
    }
  }
#undef STAGE_KV
}

// ---------------- launch ----------------
extern "C" void kernel_launch(void* const* d_in, const int* in_sizes, int n_in,
                              void* d_out, int out_size, void* d_ws, size_t ws_size,
                              hipStream_t stream) {
  const float* x  = (const float*)d_in[0];
  const float* Wq = (const float*)d_in[1];
  const float* bq = (const float*)d_in[2];
  const float* Wk = (const float*)d_in[3];
  const float* bk = (const float*)d_in[4];
  const float* Wv = (const float*)d_in[5];
  const float* bv = (const float*)d_in[6];
  const float* Wo = (const float*)d_in[7];
  const float* bo = (const float*)d_in[8];
  float* out = (float*)d_out;

  char* ws = (char*)d_ws;
  bf16* xb  = (bf16*)(ws);                     //  8,388,608 B: x bf16 [8192][512]
  bf16* wt  = (bf16*)(ws + 8388608);           //  2,097,152 B: Wt q,k,v,o [512][512] each
  bf16* qkv = (bf16*)(ws + 10485760);          // 25,165,824 B: Q|K|V [B,H,S,D] (Q x 0.125*log2e)
  bf16* mg  = (bf16*)(ws + 35651584);          //  8,388,608 B: merged [8192][512]

  prep_kernel<<<dim3(8, 8, 68), 256, 0, stream>>>(x, Wq, Wk, Wv, Wo, xb, wt);

  const float qscale = 0.125f * 1.44269504088896f;  // fold log2(e): exp -> exp2
  gemm64_kernel<128, 0><<<dim3(128, 12), 256, 0, stream>>>(
      xb, wt, bq, bk, bv, qkv, nullptr, qscale);

  bf16* qs = qkv;
  bf16* kk = qkv + 4194304;
  bf16* vv = qkv + 8388608;

  attn_kernel<<<dim3(32, 16), 512, 0, stream>>>(qs, kk, vv, mg);

  gemm64_kernel<64, 1><<<dim3(128, 8), 256, 0, stream>>>(
      mg, wt + 786432, bo, nullptr, nullptr, nullptr, out, 1.0f);
}

// Round 17
// 99.187 us; speedup vs baseline: 1.0779x; 1.0779x over previous
//
#include <hip/hip_runtime.h>
#include <hip/hip_bf16.h>
#include <stdint.h>

typedef __bf16 bf16;
typedef __bf16 bf16x2 __attribute__((ext_vector_type(2)));
typedef __bf16 bf16x4 __attribute__((ext_vector_type(4)));
typedef __bf16 bf16x8 __attribute__((ext_vector_type(8)));
typedef float f32x4 __attribute__((ext_vector_type(4)));
typedef float f32x16 __attribute__((ext_vector_type(16)));
typedef unsigned int u32x4 __attribute__((ext_vector_type(4)));
typedef int i32x2 __attribute__((ext_vector_type(2)));

#define AS1 __attribute__((address_space(1)))
#define AS3 __attribute__((address_space(3)))

// B=4 S=2048 E=512 H=8 D=64; tokens M = 8192.

// ---------------- prep (fused): z<4 -> W[z] transpose-cast; z>=4 -> x cast ----------------
__global__ void prep_kernel(const float* __restrict__ x,
                            const float* __restrict__ W0, const float* __restrict__ W1,
                            const float* __restrict__ W2, const float* __restrict__ W3,
                            bf16* __restrict__ xb, bf16* __restrict__ Wt) {
  __shared__ bf16 t[64][65];
  const int z = blockIdx.z;
  if (z < 4) {
    const float* W = z == 0 ? W0 : z == 1 ? W1 : z == 2 ? W2 : W3;
    bf16* dst = Wt + (size_t)z * 262144;
    const int c = threadIdx.x & 63, r0 = threadIdx.x >> 6;
    const int bn = blockIdx.x * 64, bk = blockIdx.y * 64;
#pragma unroll
    for (int i = 0; i < 16; ++i) {
      int r = r0 * 16 + i;
      t[c][r] = (bf16)W[(size_t)(bk + r) * 512 + bn + c];
    }
    __syncthreads();
#pragma unroll
    for (int i = 0; i < 16; ++i) {
      int n = r0 * 16 + i;
      dst[(size_t)(bn + n) * 512 + bk + c] = t[n][c];
    }
  } else {
    // cast slice: 64 z-slices x 64 blocks x 256 threads x 1 float4 = 1,048,576 float4
    int bi = (z - 4) * 64 + blockIdx.y * 8 + blockIdx.x;
    int i = bi * 256 + threadIdx.x;
    float4 v = reinterpret_cast<const float4*>(x)[i];
    bf16x4 o = { (bf16)v.x, (bf16)v.y, (bf16)v.z, (bf16)v.w };
    *reinterpret_cast<bf16x4*>(xb + (size_t)i * 4) = o;
  }
}

// ---------------- GEMM (TN), BM=64 x BN tiles (R14 proven) ----------------
// MODE 0: q/k -> bf16 scatter [B,H,S,D]; V -> TRANSPOSED Vt[bh][d][s] via LDS
//         (R17: attn stages V^T directly, deleting its VT-build phase).
// MODE 1: f32 [M][512].
template<int BN, int MODE>
__global__ __launch_bounds__(256, 4) void gemm64_kernel(
    const bf16* __restrict__ A, const bf16* __restrict__ Bt,
    const float* __restrict__ bq, const float* __restrict__ bk,
    const float* __restrict__ bv, bf16* __restrict__ out_bf,
    float* __restrict__ out_f, float qscale)
{
  constexpr int NT = BN / 32;               // per-wave n-frags (wave = 32 x BN/2)
  __shared__ union GU {
    struct { bf16 As[64 * 64]; bf16 Bs[BN * 64]; } g;
    bf16 tr[BN][72];                        // V-transpose epilogue buffer (which==2)
  } su;
  const int tid = threadIdx.x, lane = tid & 63, w = tid >> 6;
  const int wm = w >> 1, wn = w & 1;        // 2x2 wave grid
  const int m0 = blockIdx.x * 64, n0g = blockIdx.y * BN;
  const int cl = lane & 15, hi = lane >> 4;
  const int lr = lane >> 3;
  const int cofs = ((lane & 7) << 4) ^ (lr << 4);   // pre-swizzled source byte col

  f32x4 acc[2][NT] = {};

  for (int kt = 0; kt < 512; kt += 64) {
    __syncthreads();
#pragma unroll
    for (int c = 0; c < 2; ++c) {           // A: 64 rows, 2 instr/wave
      int rA = m0 + w * 16 + c * 8 + lr;
      const void* srcA = (const char*)A + ((size_t)rA * 512 + kt) * 2 + cofs;
      void* dstA = (char*)su.g.As + w * 2048 + c * 1024;
      __builtin_amdgcn_global_load_lds((const AS1 void*)srcA, (AS3 void*)dstA, 16, 0, 0);
    }
#pragma unroll
    for (int c = 0; c < NT; ++c) {          // B: BN rows, NT instr/wave
      int rB = n0g + w * (BN / 4) + c * 8 + lr;
      const void* srcB = (const char*)Bt + ((size_t)rB * 512 + kt) * 2 + cofs;
      void* dstB = (char*)su.g.Bs + w * (BN / 4) * 128 + c * 1024;
      __builtin_amdgcn_global_load_lds((const AS1 void*)srcB, (AS3 void*)dstB, 16, 0, 0);
    }
    __syncthreads();
#pragma unroll
    for (int ks = 0; ks < 2; ++ks) {
      bf16x8 af[2], bfv[NT];
#pragma unroll
      for (int mt = 0; mt < 2; ++mt) {
        int r = wm * 32 + mt * 16 + cl;
        int cb = (ks * 64 + (hi << 4)) ^ ((r & 7) << 4);
        af[mt] = *(const bf16x8*)((const char*)su.g.As + r * 128 + cb);
      }
#pragma unroll
      for (int nt = 0; nt < NT; ++nt) {
        int r = wn * (BN / 2) + nt * 16 + cl;
        int cb = (ks * 64 + (hi << 4)) ^ ((r & 7) << 4);
        bfv[nt] = *(const bf16x8*)((const char*)su.g.Bs + r * 128 + cb);
      }
#pragma unroll
      for (int mt = 0; mt < 2; ++mt)
#pragma unroll
        for (int nt = 0; nt < NT; ++nt)
          acc[mt][nt] = __builtin_amdgcn_mfma_f32_16x16x32_bf16(af[mt], bfv[nt], acc[mt][nt], 0, 0, 0);
    }
  }

  if (MODE == 0) {
    const int which = n0g >> 9;             // 0=q 1=k 2=v (BN=128 tile never straddles)
    const float* bias = which == 0 ? bq : (which == 1 ? bk : bv);
    const float scale = which == 0 ? qscale : 1.0f;
    bf16* outb = out_bf + (size_t)which * 4194304;
    const int ncol0 = n0g & 511;
    if (which == 2) {
      // ---- V: transpose via LDS, emit Vt[bh][d][s] with coalesced 128B rows ----
      __syncthreads();                      // As/Bs reads done; reuse as tr[]
#pragma unroll
      for (int mt = 0; mt < 2; ++mt) {
#pragma unroll
        for (int nt = 0; nt < NT; ++nt) {
          int dloc = wn * (BN / 2) + nt * 16 + cl;
          float bvl = bias[ncol0 + dloc];
#pragma unroll
          for (int i = 0; i < 4; ++i) {
            int s_loc = wm * 32 + mt * 16 + hi * 4 + i;
            su.tr[dloc][s_loc] = (bf16)(acc[mt][nt][i] + bvl);
          }
        }
      }
      __syncthreads();
      const int b = m0 >> 11, sbase = m0 & 2047;
#pragma unroll
      for (int pass = 0; pass < 4; ++pass) {
        int dloc = pass * 32 + (tid >> 3);
        int s0 = (tid & 7) * 8;
        int col = ncol0 + dloc;
        int h = col >> 6, d = col & 63;
        bf16x8 rowv = *(const bf16x8*)&su.tr[dloc][s0];
        *(bf16x8*)(outb + ((size_t)((b * 8 + h) * 64 + d)) * 2048 + sbase + s0) = rowv;
      }
    } else {
#pragma unroll
      for (int mt = 0; mt < 2; ++mt) {
#pragma unroll
        for (int nt = 0; nt < NT; ++nt) {
          int row0 = m0 + wm * 32 + mt * 16 + hi * 4;
          int col = ncol0 + wn * (BN / 2) + nt * 16 + cl;
          float bvl = bias[col];
          int h = col >> 6, d = col & 63;
#pragma unroll
          for (int i = 0; i < 4; ++i) {
            float vv = (acc[mt][nt][i] + bvl) * scale;
            int row = row0 + i;
            int b = row >> 11, s = row & 2047;
            outb[(((size_t)(b * 8 + h)) * 2048 + s) * 64 + d] = (bf16)vv;
          }
        }
      }
    }
  } else {
#pragma unroll
    for (int mt = 0; mt < 2; ++mt) {
#pragma unroll
      for (int nt = 0; nt < NT; ++nt) {
        int row0 = m0 + wm * 32 + mt * 16 + hi * 4;
        int col = n0g + wn * (BN / 2) + nt * 16 + cl;
        float bvl = bq[col];
#pragma unroll
        for (int i = 0; i < 4; ++i)
          out_f[(size_t)(row0 + i) * 512 + col] = acc[mt][nt][i] + bvl;
      }
    }
  }
}

// cross-half (lane ^ 32) read via v_permlane32_swap_b32 (VALU pipe)
__device__ __forceinline__ float xhalf_get(float x, int H) {
#if __has_builtin(__builtin_amdgcn_permlane32_swap)
  int xi = __builtin_bit_cast(int, x);
  i32x2 r = __builtin_amdgcn_permlane32_swap(xi, xi, false, false);
  return __builtin_bit_cast(float, H ? r[0] : r[1]);
#else
  (void)H;
  return __shfl_xor(x, 32);
#endif
}

// ---------------- flash attention, swapped-QK^T 32x32, IN-BLOCK split-KV ----------------
// grid (32 bh, 16 qb) x 512 threads (8 waves); waves 0-3 keys [0,1024), 4-7 [1024,2048).
// R17: V pre-transposed in global (Vt[bh][d][s]) -> staged directly like K with
// global_load_lds; V-lds intermediate + VT-build phase + barrier A DELETED.
// ONE barrier per KV-tile. Everything else identical to the R15/R16 proven path.
__global__ __launch_bounds__(512, 4) void attn_kernel(
    const bf16* __restrict__ q, const bf16* __restrict__ k,
    const bf16* __restrict__ vt, bf16* __restrict__ merged)
{
  __shared__ union SU {
    struct { bf16 K[2][2][4096]; bf16 VT[2][2][4096]; } s;  // [half][buf][row*64] : 64 KB
    struct {
      float EPf[4][64][33];                                  // fp32 merge buffer
      float Msh[8][32];
      float Lsh[8][32];
      bf16  EP[4][2304];                                     // per-qwave [q][72] transpose
    } e;
  } u;

  const int tid = threadIdx.x, lane = tid & 63, w = tid >> 6;
  const int wl = w & 3, half = w >> 2;
  const int l31 = lane & 31, H = lane >> 5;
  const int bh = blockIdx.x, qb = blockIdx.y;
  const int b = bh >> 3, h = bh & 7;
  const int kv0 = half << 10;       // 0 or 1024

  const bf16* Q   = q  + (size_t)bh * 2048 * 64;
  const bf16* Kp  = k  + (size_t)bh * 2048 * 64;
  const bf16* Vtp = vt + (size_t)bh * 64 * 2048;   // [d][s]

  const int q0 = qb * 128 + wl * 32;
  const int lr8 = lane >> 3;        // row within 8-row staging group
  const int lc = lane & 7;          // 16B chunk within 128B row

  // coalesced staging: K rows = keys (global stride 128B); VT rows = d (stride 4096B).
  // Both use the same pre-XOR'd source chunk so reads decode with ^((row&7)<<4).
#define STAGE_KV(BUF, KEYBASE)                                                            \
  {                                                                                       \
    _Pragma("unroll")                                                                     \
    for (int i = 0; i < 2; ++i) {                                                         \
      int row = wl * 16 + i * 8 + lr8;                                                    \
      const void* sK = (const char*)Kp + ((size_t)((KEYBASE) + row)) * 128 + ((lc ^ lr8) << 4); \
      void* dK = (char*)u.s.K[half][BUF] + wl * 2048 + i * 1024;                          \
      __builtin_amdgcn_global_load_lds((const AS1 void*)sK, (AS3 void*)dK, 16, 0, 0);     \
      const void* sV = (const char*)Vtp + (size_t)row * 4096 + (size_t)(KEYBASE) * 2 + ((lc ^ lr8) << 4); \
      void* dV = (char*)u.s.VT[half][BUF] + wl * 2048 + i * 1024;                         \
      __builtin_amdgcn_global_load_lds((const AS1 void*)sV, (AS3 void*)dV, 16, 0, 0);     \
    }                                                                                     \
  }

  // Q as B-operand frags (one-time)
  bf16x8 qf[4];
#pragma unroll
  for (int s = 0; s < 4; ++s)
    qf[s] = *(const bf16x8*)(Q + (size_t)(q0 + l31) * 64 + s * 16 + H * 8);

  f32x16 oacc[2] = {};              // O^T[d][q]: d = dt*32 + (r&3)+8*(r>>2)+4*H
  float m_run = -1e30f, l_run = 0.f;   // l_run: OWN-half sums (cross-half summed at end)

  STAGE_KV(0, kv0);
  __syncthreads();                  // buf0 ready (implicit vmcnt(0) drain)

  int cur = 0;
  for (int kt0 = kv0; kt0 < kv0 + 1024; kt0 += 64) {
    // issue next tile's K/VT staging — drains at the end-of-tile barrier
    if (kt0 + 64 < kv0 + 1024) STAGE_KV(cur ^ 1, kt0 + 64);

    const char* kb  = (const char*)u.s.K[half][cur];
    const char* vtb = (const char*)u.s.VT[half][cur];

    // ---- ct-sequential: QK^T chunk -> softmax chunk -> PV chunk (32 keys each) ----
#pragma unroll
    for (int ct = 0; ct < 2; ++ct) {
      f32x16 sc = {};
      {
        const int krow = ct * 32 + l31;
        bf16x8 kf[4];
#pragma unroll
        for (int s = 0; s < 4; ++s)
          kf[s] = *(const bf16x8*)(kb + krow * 128 + ((s * 32 + H * 16) ^ ((l31 & 7) << 4)));
#pragma unroll
        for (int s = 0; s < 4; ++s)
          sc = __builtin_amdgcn_mfma_f32_32x32x16_bf16(kf[s], qf[s], sc, 0, 0, 0);
      }

      // lane-local online softmax with defer-max (T13); max3-fused tree
      float mx[8];
#pragma unroll
      for (int r = 0; r < 8; ++r) mx[r] = fmaxf(sc[r], sc[r + 8]);
      float t0 = fmaxf(fmaxf(mx[0], mx[1]), mx[2]);
      float t1 = fmaxf(fmaxf(mx[3], mx[4]), mx[5]);
      float t2 = fmaxf(mx[6], mx[7]);
      float pmax = fmaxf(fmaxf(t0, t1), t2);
      pmax = fmaxf(pmax, xhalf_get(pmax, H));         // cross-half sync (VALU permlane)
      if (__any(pmax > m_run + 8.f)) {
        float mn = fmaxf(m_run, pmax);
        float alpha = exp2f(m_run - mn);
        m_run = mn;
        l_run *= alpha;
#pragma unroll
        for (int dt = 0; dt < 2; ++dt)
#pragma unroll
          for (int r = 0; r < 16; ++r) oacc[dt][r] *= alpha;
      }
#pragma unroll
      for (int r = 0; r < 16; ++r) sc[r] = exp2f(sc[r] - m_run);

      float sm[8];
#pragma unroll
      for (int r = 0; r < 8; ++r) sm[r] = sc[r] + sc[r + 8];
      l_run += ((sm[0] + sm[1]) + (sm[2] + sm[3])) + ((sm[4] + sm[5]) + (sm[6] + sm[7]));

      // in-register P -> bf16 B-frags (cross-half via permlane32_swap), then PV
#pragma unroll
      for (int hf = 0; hf < 2; ++hf) {
        const int ks = ct * 2 + hf;
        const int g0 = 8 * hf;
        bf16x2 pa0 = { (bf16)sc[g0 + 0], (bf16)sc[g0 + 1] };
        bf16x2 pa1 = { (bf16)sc[g0 + 2], (bf16)sc[g0 + 3] };
        bf16x2 pb0 = { (bf16)sc[g0 + 4], (bf16)sc[g0 + 5] };
        bf16x2 pb1 = { (bf16)sc[g0 + 6], (bf16)sc[g0 + 7] };
        unsigned a0 = __builtin_bit_cast(unsigned, pa0);
        unsigned a1 = __builtin_bit_cast(unsigned, pa1);
        unsigned b0 = __builtin_bit_cast(unsigned, pb0);
        unsigned b1 = __builtin_bit_cast(unsigned, pb1);
        u32x4 pw;
#if __has_builtin(__builtin_amdgcn_permlane32_swap)
        i32x2 r0 = __builtin_amdgcn_permlane32_swap((int)a0, (int)b0, false, false);
        i32x2 r1 = __builtin_amdgcn_permlane32_swap((int)a1, (int)b1, false, false);
        pw[0] = (unsigned)r0[0]; pw[1] = (unsigned)r1[0];
        pw[2] = (unsigned)r0[1]; pw[3] = (unsigned)r1[1];
#else
        unsigned oa0 = (unsigned)__shfl_xor((int)a0, 32);
        unsigned oa1 = (unsigned)__shfl_xor((int)a1, 32);
        unsigned ob0 = (unsigned)__shfl_xor((int)b0, 32);
        unsigned ob1 = (unsigned)__shfl_xor((int)b1, 32);
        pw[0] = H ? ob0 : a0; pw[1] = H ? ob1 : a1;
        pw[2] = H ? b0 : oa0; pw[3] = H ? b1 : oa1;
#endif
        bf16x8 pf = __builtin_bit_cast(bf16x8, pw);
#pragma unroll
        for (int dt = 0; dt < 2; ++dt) {
          int d = dt * 32 + l31;
          bf16x8 vf = *(const bf16x8*)(vtb + d * 128 + ((ks * 32 + H * 16) ^ ((d & 7) << 4)));
          oacc[dt] = __builtin_amdgcn_mfma_f32_32x32x16_bf16(vf, pf, oacc[dt], 0, 0, 0);
        }
      }
    }

    __syncthreads();                // prefetch landed; K/VT[cur] reads done
    cur ^= 1;
  }

  // ---- deferred cross-half l sum (m synced; both lanes of a pair share m_run) ----
  l_run += xhalf_get(l_run, H);

  // ---- in-block merge of the two key-halves (fp32 via LDS) ----
  if (H == 0) { u.e.Msh[w][l31] = m_run; u.e.Lsh[w][l31] = l_run; }
  __syncthreads();
  const int pw2 = w ^ 4;
  float m_o = u.e.Msh[pw2][l31], l_o = u.e.Lsh[pw2][l31];
  float Mt = fmaxf(m_run, m_o);
  float denom = exp2f(m_run - Mt) * l_run + exp2f(m_o - Mt) * l_o;
  float scale = exp2f(m_run - Mt) / denom;
  if (w < 4) {
    float* ep = &u.e.EPf[wl][lane][0];
#pragma unroll
    for (int dt = 0; dt < 2; ++dt)
#pragma unroll
      for (int r = 0; r < 16; ++r) ep[dt * 16 + r] = oacc[dt][r] * scale;
  }
  __syncthreads();
  if (w >= 4) {
    const float* ep = &u.e.EPf[wl][lane][0];
#pragma unroll
    for (int dt = 0; dt < 2; ++dt)
#pragma unroll
      for (int r = 0; r < 16; ++r) {
        float val = ep[dt * 16 + r] + oacc[dt][r] * scale;
        int d = dt * 32 + (r & 3) + 8 * (r >> 2) + 4 * H;
        u.e.EP[wl][l31 * 72 + d] = (bf16)val;
      }
    __builtin_amdgcn_s_waitcnt(0);  // per-wave LDS region, same-wave readback
#pragma unroll
    for (int g = 0; g < 4; ++g) {
      int qr = g * 8 + (lane >> 3);
      bf16x8 row = *(const bf16x8*)&u.e.EP[wl][qr * 72 + (lane & 7) * 8];
      *(bf16x8*)(merged + (size_t)(b * 2048 + q0 + qr) * 512 + h * 64 + (lane & 7) * 8) = row;
    }
  }
#undef STAGE_KV
}

// ---------------- launch ----------------
extern "C" void kernel_launch(void* const* d_in, const int* in_sizes, int n_in,
                              void* d_out, int out_size, void* d_ws, size_t ws_size,
                              hipStream_t stream) {
  const float* x  = (const float*)d_in[0];
  const float* Wq = (const float*)d_in[1];
  const float* bq = (const float*)d_in[2];
  const float* Wk = (const float*)d_in[3];
  const float* bk = (const float*)d_in[4];
  const float* Wv = (const float*)d_in[5];
  const float* bv = (const float*)d_in[6];
  const float* Wo = (const float*)d_in[7];
  const float* bo = (const float*)d_in[8];
  float* out = (float*)d_out;

  char* ws = (char*)d_ws;
  bf16* xb  = (bf16*)(ws);                     //  8,388,608 B: x bf16 [8192][512]
  bf16* wt  = (bf16*)(ws + 8388608);           //  2,097,152 B: Wt q,k,v,o [512][512] each
  bf16* qkv = (bf16*)(ws + 10485760);          // 25,165,824 B: Q|K|Vt (Vt transposed [bh][d][s])
  bf16* mg  = (bf16*)(ws + 35651584);          //  8,388,608 B: merged [8192][512]

  prep_kernel<<<dim3(8, 8, 68), 256, 0, stream>>>(x, Wq, Wk, Wv, Wo, xb, wt);

  const float qscale = 0.125f * 1.44269504088896f;  // fold log2(e): exp -> exp2
  gemm64_kernel<128, 0><<<dim3(128, 12), 256, 0, stream>>>(
      xb, wt, bq, bk, bv, qkv, nullptr, qscale);

  bf16* qs = qkv;
  bf16* kk = qkv + 4194304;
  bf16* vv = qkv + 8388608;                    // Vt [bh][d][s]

  attn_kernel<<<dim3(32, 16), 512, 0, stream>>>(qs, kk, vv, mg);

  gemm64_kernel<64, 1><<<dim3(128, 8), 256, 0, stream>>>(
      mg, wt + 786432, bo, nullptr, nullptr, nullptr, out, 1.0f);
}